// Round 4
// baseline (188.710 us; speedup 1.0000x reference)
//
#include <hip/hip_runtime.h>

// LocalEnergy R4: 64-row blocks (5+ blocks/CU resident), ebuf stride-24
// (bank-conflict-free gather), geom/bias folded in epilogue for all types,
// weights in registers from prepped bf16 ws. B=128, L=2048, E=16, H=128.

typedef short bf16x8 __attribute__((ext_vector_type(8)));
typedef float f32x4  __attribute__((ext_vector_type(4)));

constexpr int Lc = 2048;

union FragU { uint4 u; bf16x8 v; unsigned short s[8]; };

__device__ __forceinline__ unsigned short f2bf(float f) {
    union { float f; unsigned u; } v; v.f = f;
    unsigned u = v.u;
    u = u + 0x7FFFu + ((u >> 16) & 1u);   // RTNE
    return (unsigned short)(u >> 16);
}

__device__ __forceinline__ unsigned pkbf(float a, float b) {
    unsigned ua = __float_as_uint(a) + 0x8000u;
    unsigned ub = __float_as_uint(b) + 0x8000u;
    return __builtin_amdgcn_perm(ub, ua, 0x07060302u);
}

// ws layout (bytes):
//   W2T[t] @ t*32768           : [col2=128][k=128] bf16 k-contig   (98304)
//   W1T[t] @ 98304 + t*16384   : [hid=128][k=64]   bf16 k-contig, emb rows only
//   EB     @ 147456            : [aa=20][24] bf16 (cols 16..23 zero)
__global__ __launch_bounds__(256)
void prep_kernel(const float* __restrict__ W1_0, const float* __restrict__ W1_1,
                 const float* __restrict__ W1_2,
                 const float* __restrict__ W2_0, const float* __restrict__ W2_1,
                 const float* __restrict__ W2_2,
                 const float* __restrict__ emb, char* __restrict__ ws,
                 float* __restrict__ out)
{
    const int tid = blockIdx.x * 256 + threadIdx.x;
    const int np  = gridDim.x * 256;
    if (blockIdx.x == 0 && threadIdx.x < 128) out[threadIdx.x] = 0.0f;

    // W2^T: read coalesced (src row-major), write transposed
    unsigned short* d2 = (unsigned short*)ws;
    for (int i = tid; i < 3 * 16384; i += np) {
        int t = i >> 14, rr = i & 16383, k = rr >> 7, col = rr & 127;
        const float* W2 = (t == 0) ? W2_0 : (t == 1) ? W2_1 : W2_2;
        d2[(t << 14) + col * 128 + k] = f2bf(W2[rr]);
    }
    // W1^T (emb rows only; geom rows + b1 folded in energy epilogue)
    unsigned short* d1 = (unsigned short*)(ws + 98304);
    for (int i = tid; i < 3 * 8192; i += np) {
        int t = i >> 13, r = i & 8191, hid = r >> 6, k = r & 63;
        const int NE16 = (t == 0) ? 32 : (t == 1) ? 48 : 64;
        const int NG   = (t == 2) ? 2 : 1;
        const float* W1 = (t == 0) ? W1_0 : (t == 1) ? W1_1 : W1_2;
        d1[i] = (k < NE16) ? f2bf(W1[(NG + k) * 128 + hid]) : (unsigned short)0;
    }
    // emb bf16 table, stride 24
    unsigned short* eb = (unsigned short*)(ws + 147456);
    for (int i = tid; i < 480; i += np) {
        int aa = i / 24, e = i - aa * 24;
        eb[i] = (e < 16) ? f2bf(emb[aa * 16 + e]) : (unsigned short)0;
    }
}

struct SMem {
    unsigned short H1s[64 * 136];   // 17408 B
    float  Rbuf[204];               // 67 rows x 3
    float  geomb[128];              // [2][64]
    int    seqb[68];
    unsigned short ebuf[20 * 24];   // stride-24 bf16 table
    float  part[4];
};

template<int TYPE>
__device__ __forceinline__ void body(
    SMem* sm,
    const float* __restrict__ R, const int* __restrict__ seq,
    const char* __restrict__ ws,
    const float* __restrict__ W1, const float* __restrict__ b1,
    const float* __restrict__ b2, const float* __restrict__ w3,
    const float* __restrict__ b3, float* __restrict__ out)
{
    constexpr int NEMB  = (TYPE == 0) ? 2 : (TYPE == 1) ? 3 : 4;
    constexpr int SB    = NEMB * 16;
    constexpr int NG    = (TYPE == 2) ? 2 : 1;
    constexpr int KS1   = (TYPE == 0) ? 1 : 2;
    constexpr int ROWSB = Lc - 1 - TYPE;
    constexpr int SHs   = 136;

    const int tid = threadIdx.x;
    const int b   = blockIdx.y;
    const int i0  = blockIdx.x * 64;
    const int lane = tid & 63, wv = tid >> 6;
    const int q = lane >> 4, c = lane & 15;

    const unsigned short* w1t = (const unsigned short*)(ws + 98304 + TYPE * 16384);
    const unsigned short* w2t = (const unsigned short*)(ws + TYPE * 32768);

    // ---- GEMM1 A-frags (W1t) ----
    FragU A1[2][2];
#pragma unroll
    for (int mt = 0; mt < 2; ++mt)
#pragma unroll
        for (int ks = 0; ks < KS1; ++ks)
            A1[mt][ks].u = *(const uint4*)&w1t[(wv * 32 + mt * 16 + c) * 64 + ks * 32 + q * 8];

    // ---- stage R / seq / ebuf ----
    for (int t = tid; t < 201; t += 256) {
        int lr = t / 3, comp = t - lr * 3;
        int row = min(i0 + lr, Lc - 1);
        sm->Rbuf[t] = R[((size_t)b * Lc + row) * 3 + comp];
    }
    for (int t = tid; t < 67; t += 256)
        sm->seqb[t] = seq[b * Lc + min(i0 + t, Lc - 1)];
    {
        const uint4* se = (const uint4*)(ws + 147456);
        for (int t = tid; t < 60; t += 256) ((uint4*)sm->ebuf)[t] = se[t];
    }
    __syncthreads();

    // ---- geometry (threads 0..63) ----
    if (tid < 64) {
        const float* p0 = &sm->Rbuf[tid * 3];
        float ax = p0[3] - p0[0], ay = p0[4] - p0[1], az = p0[5] - p0[2];
        float g0 = 0.f, g1 = 0.f;
        if (TYPE == 0) {
            g0 = sqrtf(ax * ax + ay * ay + az * az);
        } else if (TYPE == 1) {
            float bx = p0[6] - p0[3], by = p0[7] - p0[4], bz = p0[8] - p0[5];
            float duv = -(ax * bx + ay * by + az * bz);
            float na2 = ax * ax + ay * ay + az * az;
            float nb2 = bx * bx + by * by + bz * bz;
            float cosv = duv / sqrtf(na2 * nb2);
            g0 = fminf(fmaxf(cosv, -1.0f), 1.0f);
        } else {
            float bx = p0[6] - p0[3], by = p0[7] - p0[4], bz = p0[8] - p0[5];
            float cx = p0[9] - p0[6], cy = p0[10] - p0[7], cz = p0[11] - p0[8];
            float n1x = ay * bz - az * by, n1y = az * bx - ax * bz, n1z = ax * by - ay * bx;
            float n2x = by * cz - bz * cy, n2y = bz * cx - bx * cz, n2z = bx * cy - by * cx;
            float binv = 1.0f / sqrtf(bx * bx + by * by + bz * bz);
            float ux = bx * binv, uy = by * binv, uz = bz * binv;
            float m1x = n1y * uz - n1z * uy, m1y = n1z * ux - n1x * uz, m1z = n1x * uy - n1y * ux;
            float yv = m1x * n2x + m1y * n2y + m1z * n2z;
            float xv = n1x * n2x + n1y * n2y + n1z * n2z;
            float inv = 1.0f / sqrtf(xv * xv + yv * yv);
            g0 = yv * inv; g1 = xv * inv;
        }
        sm->geomb[tid] = g0;
        sm->geomb[64 + tid] = g1;
    }
    __syncthreads();

    // ---- GEMM1 (swapped): acc1[mt][nt] = D[hid][row], K = emb features only ----
    f32x4 acc1[2][4];
#pragma unroll
    for (int mt = 0; mt < 2; ++mt)
#pragma unroll
        for (int nt = 0; nt < 4; ++nt)
            acc1[mt][nt] = (f32x4){0.f, 0.f, 0.f, 0.f};

#pragma unroll
    for (int ks = 0; ks < KS1; ++ks) {
        const int kb = ks * 32 + q * 8;
        const int j = kb >> 4, off = kb & 15;
#pragma unroll
        for (int nt = 0; nt < 4; ++nt) {
            const int m = nt * 16 + c;
            FragU bb;
            if (kb < SB)
                bb.u = *(const uint4*)&sm->ebuf[sm->seqb[m + j] * 24 + off];
            else
                bb.u = make_uint4(0u, 0u, 0u, 0u);
            acc1[0][nt] = __builtin_amdgcn_mfma_f32_16x16x32_bf16(A1[0][ks].v, bb.v, acc1[0][nt], 0, 0, 0);
            acc1[1][nt] = __builtin_amdgcn_mfma_f32_16x16x32_bf16(A1[1][ks].v, bb.v, acc1[1][nt], 0, 0, 0);
        }
    }

    // ---- load epilogue constants + W2 B-frags (L2-hot; overlaps MFMA drain) ----
    float b1v[8], g0v[8], g1v[8];
#pragma unroll
    for (int mt = 0; mt < 2; ++mt)
#pragma unroll
        for (int rg = 0; rg < 4; ++rg) {
            int hid = wv * 32 + mt * 16 + q * 4 + rg;
            b1v[mt * 4 + rg] = b1[hid];
            g0v[mt * 4 + rg] = W1[hid];
            if (NG == 2) g1v[mt * 4 + rg] = W1[128 + hid];
        }
    FragU B2[2][4];
#pragma unroll
    for (int nt = 0; nt < 2; ++nt)
#pragma unroll
        for (int ks = 0; ks < 4; ++ks)
            B2[nt][ks].u = *(const uint4*)&w2t[(wv * 32 + nt * 16 + c) * 128 + ks * 32 + q * 8];
    float b2v[2], w3v[2];
#pragma unroll
    for (int nt = 0; nt < 2; ++nt) {
        int col2 = wv * 32 + nt * 16 + c;
        b2v[nt] = b2[col2]; w3v[nt] = w3[col2];
    }

    // ---- H1 = relu(acc1 + geom*w1g + b1) -> H1s (packed 8B writes) ----
    float gm0[4], gm1[4];
#pragma unroll
    for (int nt = 0; nt < 4; ++nt) {
        gm0[nt] = sm->geomb[nt * 16 + c];
        if (NG == 2) gm1[nt] = sm->geomb[64 + nt * 16 + c];
    }
#pragma unroll
    for (int mt = 0; mt < 2; ++mt)
#pragma unroll
        for (int nt = 0; nt < 4; ++nt) {
            const int m = nt * 16 + c;
            float v0 = acc1[mt][nt][0] + gm0[nt] * g0v[mt * 4 + 0] + b1v[mt * 4 + 0];
            float v1 = acc1[mt][nt][1] + gm0[nt] * g0v[mt * 4 + 1] + b1v[mt * 4 + 1];
            float v2 = acc1[mt][nt][2] + gm0[nt] * g0v[mt * 4 + 2] + b1v[mt * 4 + 2];
            float v3 = acc1[mt][nt][3] + gm0[nt] * g0v[mt * 4 + 3] + b1v[mt * 4 + 3];
            if (NG == 2) {
                v0 += gm1[nt] * g1v[mt * 4 + 0];
                v1 += gm1[nt] * g1v[mt * 4 + 1];
                v2 += gm1[nt] * g1v[mt * 4 + 2];
                v3 += gm1[nt] * g1v[mt * 4 + 3];
            }
            v0 = fmaxf(v0, 0.f); v1 = fmaxf(v1, 0.f);
            v2 = fmaxf(v2, 0.f); v3 = fmaxf(v3, 0.f);
            uint2 pk;
            pk.x = pkbf(v0, v1);
            pk.y = pkbf(v2, v3);
            *(uint2*)&sm->H1s[m * SHs + wv * 32 + mt * 16 + q * 4] = pk;
        }
    __syncthreads();

    // ---- GEMM2: acc2[mt][nt] = D[row][col2] ----
    f32x4 acc2[4][2];
#pragma unroll
    for (int mt = 0; mt < 4; ++mt)
#pragma unroll
        for (int nt = 0; nt < 2; ++nt)
            acc2[mt][nt] = (f32x4){0.f, 0.f, 0.f, 0.f};

#pragma unroll
    for (int ks = 0; ks < 4; ++ks)
#pragma unroll
        for (int mt = 0; mt < 4; ++mt) {
            bf16x8 aa = *(const bf16x8*)&sm->H1s[(mt * 16 + c) * SHs + ks * 32 + q * 8];
            acc2[mt][0] = __builtin_amdgcn_mfma_f32_16x16x32_bf16(aa, B2[0][ks].v, acc2[mt][0], 0, 0, 0);
            acc2[mt][1] = __builtin_amdgcn_mfma_f32_16x16x32_bf16(aa, B2[1][ks].v, acc2[mt][1], 0, 0, 0);
        }

    // ---- epilogue: sum relu(h2+b2)*w3 over this wave's col2 chunk ----
    float p = 0.0f;
#pragma unroll
    for (int mt = 0; mt < 4; ++mt)
#pragma unroll
        for (int rg = 0; rg < 4; ++rg) {
            int m = mt * 16 + q * 4 + rg;
            if (i0 + m < ROWSB) {
                p += fmaxf(acc2[mt][0][rg] + b2v[0], 0.f) * w3v[0];
                p += fmaxf(acc2[mt][1][rg] + b2v[1], 0.f) * w3v[1];
            }
        }
#pragma unroll
    for (int off = 32; off > 0; off >>= 1)
        p += __shfl_down(p, off);
    if (lane == 0) sm->part[wv] = p;
    __syncthreads();
    if (tid == 0) {
        int vc = min(ROWSB - i0, 64);
        atomicAdd(&out[b], sm->part[0] + sm->part[1] + sm->part[2] + sm->part[3]
                           + b3[0] * (float)vc);
    }
}

__global__ __launch_bounds__(256, 5)
void energy_kernel(const float* __restrict__ R, const int* __restrict__ seq,
                   const char* __restrict__ ws,
                   const float* W1_0, const float* b1_0,
                   const float* W1_1, const float* b1_1,
                   const float* W1_2, const float* b1_2,
                   const float* b2_0, const float* b2_1, const float* b2_2,
                   const float* w3_0, const float* w3_1, const float* w3_2,
                   const float* b3_0, const float* b3_1, const float* b3_2,
                   float* out)
{
    __shared__ SMem sm;
    if (blockIdx.z == 0)
        body<0>(&sm, R, seq, ws, W1_0, b1_0, b2_0, w3_0, b3_0, out);
    else if (blockIdx.z == 1)
        body<1>(&sm, R, seq, ws, W1_1, b1_1, b2_1, w3_1, b3_1, out);
    else
        body<2>(&sm, R, seq, ws, W1_2, b1_2, b2_2, w3_2, b3_2, out);
}

extern "C" void kernel_launch(void* const* d_in, const int* in_sizes, int n_in,
                              void* d_out, int out_size, void* d_ws, size_t ws_size,
                              hipStream_t stream) {
    const float* R   = (const float*)d_in[0];
    const int*   seq = (const int*)d_in[1];
    const float* emb = (const float*)d_in[2];
    float* out = (float*)d_out;
    char*  ws  = (char*)d_ws;

    prep_kernel<<<dim3(96), dim3(256), 0, stream>>>(
        (const float*)d_in[3], (const float*)d_in[9], (const float*)d_in[15],
        (const float*)d_in[5], (const float*)d_in[11], (const float*)d_in[17],
        emb, ws, out);

    dim3 grid(32, 128, 3), block(256);
    energy_kernel<<<grid, block, 0, stream>>>(
        R, seq, ws,
        (const float*)d_in[3],  (const float*)d_in[4],
        (const float*)d_in[9],  (const float*)d_in[10],
        (const float*)d_in[15], (const float*)d_in[16],
        (const float*)d_in[6],  (const float*)d_in[12], (const float*)d_in[18],
        (const float*)d_in[7],  (const float*)d_in[13], (const float*)d_in[19],
        (const float*)d_in[8],  (const float*)d_in[14], (const float*)d_in[20],
        out);
}